// Round 1
// baseline (4246.278 us; speedup 1.0000x reference)
//
#include <hip/hip_runtime.h>

#define B_ROWS 8192
#define UNITS 512
#define NITER 25
#define INSZ 176
#define KPAD 128
#define GRAD_COLS 101

typedef __attribute__((ext_vector_type(8))) short short8;
typedef __attribute__((ext_vector_type(4))) float f32x4;
typedef __attribute__((ext_vector_type(8))) __bf16 bf16x8;

__device__ __forceinline__ float b2f(unsigned short s) {
  return __builtin_bit_cast(float, (unsigned)s << 16);
}
__device__ __forceinline__ unsigned short f2b(float f) {
  unsigned u = __builtin_bit_cast(unsigned, f);
  u += 0x7fff + ((u >> 16) & 1);   // RNE
  return (unsigned short)(u >> 16);
}
__device__ __forceinline__ void split2(float v, unsigned short& hi, unsigned short& lo) {
  hi = f2b(v);
  lo = f2b(v - b2f(hi));
}
__device__ __forceinline__ float fast_tanh(float x) {
  float e = __expf(2.0f * x);
  return 1.0f - 2.0f / (e + 1.0f);
}

typedef __attribute__((address_space(3))) unsigned int lds_u32;
typedef __attribute__((address_space(1))) const unsigned int glb_u32;
__device__ __forceinline__ void gload16(const void* g, void* l) {
  __builtin_amdgcn_global_load_lds((glb_u32*)g, (lds_u32*)l, 16, 0, 0);
}

// ---------------------------------------------------------------------------
// Weight prep: split-bf16 planes, n-major ("B-transposed") layouts, zero-padded.
// TW0[n][k]=W0[k][n] (512x128, k pad 101->128)   : fwd layer0 operand
// TWi[n][k]=Wi[k][n] (512x512)                   : fwd layers 1-3
// CW0[n][k]=W0[n][k] (128x512, n pad 101->128)   : bwd grad operand (W0^T n-major)
// CWi[n][k]=Wi[n][k] (512x512)                   : bwd operands (Wi^T n-major)
// ---------------------------------------------------------------------------
__global__ __launch_bounds__(256)
void prep_kernel(const float* __restrict__ W0, const float* __restrict__ W1,
                 const float* __restrict__ W2, const float* __restrict__ W3,
                 unsigned short* TW0hi, unsigned short* TW0lo,
                 unsigned short* TW1hi, unsigned short* TW1lo,
                 unsigned short* TW2hi, unsigned short* TW2lo,
                 unsigned short* TW3hi, unsigned short* TW3lo,
                 unsigned short* CW0hi, unsigned short* CW0lo,
                 unsigned short* CW1hi, unsigned short* CW1lo,
                 unsigned short* CW2hi, unsigned short* CW2lo,
                 unsigned short* CW3hi, unsigned short* CW3lo)
{
  int id = blockIdx.x * 256 + threadIdx.x;   // [0, 512*512)
  unsigned short hi, lo;
  if (id < 512 * KPAD) {
    int n = id >> 7, k = id & (KPAD - 1);
    float v = (k < 101) ? W0[(size_t)k * 512 + n] : 0.0f;
    split2(v, hi, lo); TW0hi[id] = hi; TW0lo[id] = lo;
    int n2 = id >> 9, k2 = id & 511;
    float v2 = (n2 < 101) ? W0[(size_t)n2 * 512 + k2] : 0.0f;
    split2(v2, hi, lo); CW0hi[id] = hi; CW0lo[id] = lo;
  }
  {
    int n = id >> 9, k = id & 511;
    float t;
    t = W1[(size_t)k * 512 + n]; split2(t, hi, lo); TW1hi[id] = hi; TW1lo[id] = lo;
    t = W2[(size_t)k * 512 + n]; split2(t, hi, lo); TW2hi[id] = hi; TW2lo[id] = lo;
    t = W3[(size_t)k * 512 + n]; split2(t, hi, lo); TW3hi[id] = hi; TW3lo[id] = lo;
    t = W1[id]; split2(t, hi, lo); CW1hi[id] = hi; CW1lo[id] = lo;
    t = W2[id]; split2(t, hi, lo); CW2hi[id] = hi; CW2lo[id] = lo;
    t = W3[id]; split2(t, hi, lo); CW3hi[id] = hi; CW3lo[id] = lo;
  }
}

// ---------------------------------------------------------------------------
// build D_i (8192 x 128, split planes), zero-padded cols 101..127
// ---------------------------------------------------------------------------
__global__ __launch_bounds__(256)
void build_d_kernel(const float* __restrict__ x, const float* __restrict__ w_out,
                    unsigned short* __restrict__ Dhi, unsigned short* __restrict__ Dlo,
                    int iter)
{
  int id = blockIdx.x * 256 + threadIdx.x;     // [0, 8192*128)
  int b = id >> 7, c = id & 127;
  float val;
  if (c < 25 - iter)      val = x[(size_t)b * INSZ + iter + c];
  else if (c < 25)        val = w_out[(size_t)b * NITER + (c - (25 - iter))];
  else if (c < 100)       val = x[(size_t)b * INSZ + 26 + 3 * iter + (c - 25)];
  else if (c == 100)      val = (float)iter;
  else                    val = 0.0f;
  unsigned short hi, lo; split2(val, hi, lo);
  Dhi[id] = hi; Dlo[id] = lo;
}

// ---------------------------------------------------------------------------
// GEMM: C[M=8192 x N] = A[M x K] @ B(n-major)[N x K], split-bf16, 3-product.
// 128x128 tile, BK=64, 4 waves (2x2), 4x4 16x16x32 frags/wave.
// EPI 0: tanh(acc + bias[n]) -> split store to O planes (stride UNITS)
// EPI 1: acc * (1 - h^2) (h from H planes) -> split store to O planes
// EPI 2: grad store: Og[(m*25+iter)*101+n] = acc  (n < 101)
// ---------------------------------------------------------------------------
template<int EPI>
__global__ __launch_bounds__(256, 2)
void gemm_kernel(const unsigned short* __restrict__ Ahi, const unsigned short* __restrict__ Alo,
                 const unsigned short* __restrict__ Bhi, const unsigned short* __restrict__ Blo,
                 int K,
                 const float* __restrict__ bias,
                 const unsigned short* __restrict__ Hhi, const unsigned short* __restrict__ Hlo,
                 unsigned short* __restrict__ Ohi, unsigned short* __restrict__ Olo,
                 float* __restrict__ Og, int iter)
{
  alignas(16) __shared__ short As_hi[128 * 64];
  alignas(16) __shared__ short As_lo[128 * 64];
  alignas(16) __shared__ short Bs_hi[128 * 64];
  alignas(16) __shared__ short Bs_lo[128 * 64];

  const int t = threadIdx.x;
  const int w = t >> 6;
  const int lane = t & 63;
  const int l15 = lane & 15, l4 = lane >> 4;
  const int bm = blockIdx.x, bn = blockIdx.y;
  const int wm = (w >> 1) * 64, wn = (w & 1) * 64;
  f32x4 acc[4][4] = {};

  const int sr = t >> 3;   // 0..31 (row within 32-row round)
  const int ss = t & 7;    // linear 16B slot within 128B row

  for (int kc = 0; kc < K; kc += 64) {
    __syncthreads();
#pragma unroll
    for (int q = 0; q < 4; ++q) {
      int r = q * 32 + sr;
      int c = ss ^ (r & 7);                          // inverse-swizzled source slot
      size_t ga = (size_t)(bm * 128 + r) * K + kc + c * 8;
      size_t gb = (size_t)(bn * 128 + r) * K + kc + c * 8;
      int ldst = q * 2048 + w * 512;                 // wave-uniform LDS base (shorts)
      gload16(Ahi + ga, &As_hi[ldst]);
      gload16(Alo + ga, &As_lo[ldst]);
      gload16(Bhi + gb, &Bs_hi[ldst]);
      gload16(Blo + gb, &Bs_lo[ldst]);
    }
    __syncthreads();
#pragma unroll
    for (int kk = 0; kk < 2; ++kk) {
      short8 ah[4], al[4], bh[4], bl[4];
#pragma unroll
      for (int mi = 0; mi < 4; ++mi) {
        int row = wm + mi * 16 + l15;
        int eoff = row * 64 + (((kk * 4 + l4) ^ (row & 7)) << 3);
        ah[mi] = *(const short8*)&As_hi[eoff];
        al[mi] = *(const short8*)&As_lo[eoff];
      }
#pragma unroll
      for (int ni = 0; ni < 4; ++ni) {
        int row = wn + ni * 16 + l15;
        int eoff = row * 64 + (((kk * 4 + l4) ^ (row & 7)) << 3);
        bh[ni] = *(const short8*)&Bs_hi[eoff];
        bl[ni] = *(const short8*)&Bs_lo[eoff];
      }
#pragma unroll
      for (int mi = 0; mi < 4; ++mi)
#pragma unroll
        for (int ni = 0; ni < 4; ++ni) {
          acc[mi][ni] = __builtin_amdgcn_mfma_f32_16x16x32_bf16(
              __builtin_bit_cast(bf16x8, ah[mi]), __builtin_bit_cast(bf16x8, bh[ni]),
              acc[mi][ni], 0, 0, 0);
          acc[mi][ni] = __builtin_amdgcn_mfma_f32_16x16x32_bf16(
              __builtin_bit_cast(bf16x8, ah[mi]), __builtin_bit_cast(bf16x8, bl[ni]),
              acc[mi][ni], 0, 0, 0);
          acc[mi][ni] = __builtin_amdgcn_mfma_f32_16x16x32_bf16(
              __builtin_bit_cast(bf16x8, al[mi]), __builtin_bit_cast(bf16x8, bh[ni]),
              acc[mi][ni], 0, 0, 0);
        }
    }
  }

  const int gm0 = bm * 128 + wm;
  const int gn0 = bn * 128 + wn;
#pragma unroll
  for (int mi = 0; mi < 4; ++mi) {
#pragma unroll
    for (int ni = 0; ni < 4; ++ni) {
      int n = gn0 + ni * 16 + l15;
#pragma unroll
      for (int r = 0; r < 4; ++r) {
        int m = gm0 + mi * 16 + l4 * 4 + r;
        float v = acc[mi][ni][r];
        if constexpr (EPI == 0) {
          float h = fast_tanh(v + bias[n]);
          unsigned short hi, lo; split2(h, hi, lo);
          size_t idx = (size_t)m * UNITS + n;
          Ohi[idx] = hi; Olo[idx] = lo;
        } else if constexpr (EPI == 1) {
          size_t idx = (size_t)m * UNITS + n;
          float h = b2f(Hhi[idx]) + b2f(Hlo[idx]);
          float u = v * (1.0f - h * h);
          unsigned short hi, lo; split2(u, hi, lo);
          Ohi[idx] = hi; Olo[idx] = lo;
        } else {
          if (n < GRAD_COLS)
            Og[((size_t)m * NITER + iter) * GRAD_COLS + n] = v;
        }
      }
    }
  }
}

// ---------------------------------------------------------------------------
// Per-row dot (w[:,i] = H3.W4 + b4) fused with U3 = (1-H3^2) * W4
// one wave per row
// ---------------------------------------------------------------------------
__global__ __launch_bounds__(256)
void dot_u3_kernel(const unsigned short* __restrict__ H3hi, const unsigned short* __restrict__ H3lo,
                   const float* __restrict__ W4, const float* __restrict__ b4,
                   float* __restrict__ w_out,
                   unsigned short* __restrict__ Uhi, unsigned short* __restrict__ Ulo,
                   int iter)
{
  int w = threadIdx.x >> 6, lane = threadIdx.x & 63;
  int b = blockIdx.x * 4 + w;
  size_t base = (size_t)b * UNITS + lane * 8;
  short8 vhi = *(const short8*)&H3hi[base];
  short8 vlo = *(const short8*)&H3lo[base];
  float dot = 0.0f;
  short8 ohi, olo;
#pragma unroll
  for (int j = 0; j < 8; ++j) {
    float h = b2f((unsigned short)vhi[j]) + b2f((unsigned short)vlo[j]);
    float g = W4[lane * 8 + j];
    dot += h * g;
    float u = (1.0f - h * h) * g;
    unsigned short hi, lo; split2(u, hi, lo);
    ohi[j] = (short)hi; olo[j] = (short)lo;
  }
  *(short8*)&Uhi[base] = ohi;
  *(short8*)&Ulo[base] = olo;
#pragma unroll
  for (int off = 1; off < 64; off <<= 1) dot += __shfl_xor(dot, off);
  if (lane == 0) w_out[(size_t)b * NITER + iter] = dot + b4[0];
}

// ---------------------------------------------------------------------------
extern "C" void kernel_launch(void* const* d_in, const int* in_sizes, int n_in,
                              void* d_out, int out_size, void* d_ws, size_t ws_size,
                              hipStream_t stream) {
  const float* x  = (const float*)d_in[0];
  const float* W0 = (const float*)d_in[1];
  const float* b0 = (const float*)d_in[2];
  const float* W1 = (const float*)d_in[3];
  const float* b1 = (const float*)d_in[4];
  const float* W2 = (const float*)d_in[5];
  const float* b2 = (const float*)d_in[6];
  const float* W3 = (const float*)d_in[7];
  const float* b3 = (const float*)d_in[8];
  const float* W4 = (const float*)d_in[9];
  const float* b4 = (const float*)d_in[10];

  float* w_out    = (float*)d_out;                              // (8192, 25)
  float* grad_out = (float*)d_out + (size_t)B_ROWS * NITER;     // (8192, 25, 101)

  char* p = (char*)d_ws;
  auto alloc = [&](size_t elems) { unsigned short* r = (unsigned short*)p; p += elems * 2; return r; };

  unsigned short* TW0hi = alloc(512 * KPAD); unsigned short* TW0lo = alloc(512 * KPAD);
  unsigned short* TW1hi = alloc(512 * 512);  unsigned short* TW1lo = alloc(512 * 512);
  unsigned short* TW2hi = alloc(512 * 512);  unsigned short* TW2lo = alloc(512 * 512);
  unsigned short* TW3hi = alloc(512 * 512);  unsigned short* TW3lo = alloc(512 * 512);
  unsigned short* CW0hi = alloc(KPAD * 512); unsigned short* CW0lo = alloc(KPAD * 512);
  unsigned short* CW1hi = alloc(512 * 512);  unsigned short* CW1lo = alloc(512 * 512);
  unsigned short* CW2hi = alloc(512 * 512);  unsigned short* CW2lo = alloc(512 * 512);
  unsigned short* CW3hi = alloc(512 * 512);  unsigned short* CW3lo = alloc(512 * 512);

  unsigned short* Dhi = alloc((size_t)B_ROWS * KPAD);
  unsigned short* Dlo = alloc((size_t)B_ROWS * KPAD);
  unsigned short* H0hi = alloc((size_t)B_ROWS * UNITS); unsigned short* H0lo = alloc((size_t)B_ROWS * UNITS);
  unsigned short* H1hi = alloc((size_t)B_ROWS * UNITS); unsigned short* H1lo = alloc((size_t)B_ROWS * UNITS);
  unsigned short* H2hi = alloc((size_t)B_ROWS * UNITS); unsigned short* H2lo = alloc((size_t)B_ROWS * UNITS);
  unsigned short* H3hi = alloc((size_t)B_ROWS * UNITS); unsigned short* H3lo = alloc((size_t)B_ROWS * UNITS);
  unsigned short* Uahi = alloc((size_t)B_ROWS * UNITS); unsigned short* Ualo = alloc((size_t)B_ROWS * UNITS);
  unsigned short* Ubhi = alloc((size_t)B_ROWS * UNITS); unsigned short* Ublo = alloc((size_t)B_ROWS * UNITS);

  prep_kernel<<<1024, 256, 0, stream>>>(W0, W1, W2, W3,
      TW0hi, TW0lo, TW1hi, TW1lo, TW2hi, TW2lo, TW3hi, TW3lo,
      CW0hi, CW0lo, CW1hi, CW1lo, CW2hi, CW2lo, CW3hi, CW3lo);

  for (int i = 0; i < NITER; ++i) {
    build_d_kernel<<<4096, 256, 0, stream>>>(x, w_out, Dhi, Dlo, i);
    // forward
    gemm_kernel<0><<<dim3(64, 4), 256, 0, stream>>>(Dhi, Dlo, TW0hi, TW0lo, KPAD, b0,
        nullptr, nullptr, H0hi, H0lo, nullptr, 0);
    gemm_kernel<0><<<dim3(64, 4), 256, 0, stream>>>(H0hi, H0lo, TW1hi, TW1lo, 512, b1,
        nullptr, nullptr, H1hi, H1lo, nullptr, 0);
    gemm_kernel<0><<<dim3(64, 4), 256, 0, stream>>>(H1hi, H1lo, TW2hi, TW2lo, 512, b2,
        nullptr, nullptr, H2hi, H2lo, nullptr, 0);
    gemm_kernel<0><<<dim3(64, 4), 256, 0, stream>>>(H2hi, H2lo, TW3hi, TW3lo, 512, b3,
        nullptr, nullptr, H3hi, H3lo, nullptr, 0);
    // head + start of backward
    dot_u3_kernel<<<2048, 256, 0, stream>>>(H3hi, H3lo, W4, b4, w_out, Uahi, Ualo, i);
    // backward
    gemm_kernel<1><<<dim3(64, 4), 256, 0, stream>>>(Uahi, Ualo, CW3hi, CW3lo, 512, nullptr,
        H2hi, H2lo, Ubhi, Ublo, nullptr, 0);
    gemm_kernel<1><<<dim3(64, 4), 256, 0, stream>>>(Ubhi, Ublo, CW2hi, CW2lo, 512, nullptr,
        H1hi, H1lo, Uahi, Ualo, nullptr, 0);
    gemm_kernel<1><<<dim3(64, 4), 256, 0, stream>>>(Uahi, Ualo, CW1hi, CW1lo, 512, nullptr,
        H0hi, H0lo, Ubhi, Ublo, nullptr, 0);
    gemm_kernel<2><<<dim3(64, 1), 256, 0, stream>>>(Ubhi, Ublo, CW0hi, CW0lo, 512, nullptr,
        nullptr, nullptr, nullptr, nullptr, grad_out, i);
  }

  (void)in_sizes; (void)n_in; (void)out_size; (void)ws_size;
}

// Round 2
// 3380.246 us; speedup vs baseline: 1.2562x; 1.2562x over previous
//
#include <hip/hip_runtime.h>

#define B_ROWS 8192
#define UNITS 512
#define NITER 25
#define INSZ 176
#define KPAD 128
#define GRAD_COLS 101

typedef __attribute__((ext_vector_type(8))) short short8;
typedef __attribute__((ext_vector_type(4))) float f32x4;
typedef __attribute__((ext_vector_type(8))) __bf16 bf16x8;

__device__ __forceinline__ float b2f(unsigned short s) {
  return __builtin_bit_cast(float, (unsigned)s << 16);
}
__device__ __forceinline__ unsigned short f2b(float f) {
  unsigned u = __builtin_bit_cast(unsigned, f);
  u += 0x7fff + ((u >> 16) & 1);   // RNE
  return (unsigned short)(u >> 16);
}
__device__ __forceinline__ void split2(float v, unsigned short& hi, unsigned short& lo) {
  hi = f2b(v);
  lo = f2b(v - b2f(hi));
}
__device__ __forceinline__ float fast_tanh(float x) {
  float e = __expf(2.0f * x);
  return 1.0f - 2.0f / (e + 1.0f);
}

typedef __attribute__((address_space(3))) unsigned int lds_u32;
typedef __attribute__((address_space(1))) const unsigned int glb_u32;
__device__ __forceinline__ void gload16(const void* g, void* l) {
  __builtin_amdgcn_global_load_lds((glb_u32*)g, (lds_u32*)l, 16, 0, 0);
}

struct GArgs {
  const unsigned short *Ahi, *Alo, *Bhi, *Blo;
  int K;
  const float* bias;
  const unsigned short *Hhi, *Hlo;
  unsigned short *Ohi, *Olo;
  float* Og;
  int iter;
};

// ---------------------------------------------------------------------------
// Weight prep (unchanged from round 1)
// ---------------------------------------------------------------------------
__global__ __launch_bounds__(256)
void prep_kernel(const float* __restrict__ W0, const float* __restrict__ W1,
                 const float* __restrict__ W2, const float* __restrict__ W3,
                 unsigned short* TW0hi, unsigned short* TW0lo,
                 unsigned short* TW1hi, unsigned short* TW1lo,
                 unsigned short* TW2hi, unsigned short* TW2lo,
                 unsigned short* TW3hi, unsigned short* TW3lo,
                 unsigned short* CW0hi, unsigned short* CW0lo,
                 unsigned short* CW1hi, unsigned short* CW1lo,
                 unsigned short* CW2hi, unsigned short* CW2lo,
                 unsigned short* CW3hi, unsigned short* CW3lo)
{
  int id = blockIdx.x * 256 + threadIdx.x;
  unsigned short hi, lo;
  if (id < 512 * KPAD) {
    int n = id >> 7, k = id & (KPAD - 1);
    float v = (k < 101) ? W0[(size_t)k * 512 + n] : 0.0f;
    split2(v, hi, lo); TW0hi[id] = hi; TW0lo[id] = lo;
    int n2 = id >> 9, k2 = id & 511;
    float v2 = (n2 < 101) ? W0[(size_t)n2 * 512 + k2] : 0.0f;
    split2(v2, hi, lo); CW0hi[id] = hi; CW0lo[id] = lo;
  }
  {
    int n = id >> 9, k = id & 511;
    float t;
    t = W1[(size_t)k * 512 + n]; split2(t, hi, lo); TW1hi[id] = hi; TW1lo[id] = lo;
    t = W2[(size_t)k * 512 + n]; split2(t, hi, lo); TW2hi[id] = hi; TW2lo[id] = lo;
    t = W3[(size_t)k * 512 + n]; split2(t, hi, lo); TW3hi[id] = hi; TW3lo[id] = lo;
    t = W1[id]; split2(t, hi, lo); CW1hi[id] = hi; CW1lo[id] = lo;
    t = W2[id]; split2(t, hi, lo); CW2hi[id] = hi; CW2lo[id] = lo;
    t = W3[id]; split2(t, hi, lo); CW3hi[id] = hi; CW3lo[id] = lo;
  }
}

// ---------------------------------------------------------------------------
// Initial build D_0 (8192 x 128, split planes), zero-padded cols 101..127
// ---------------------------------------------------------------------------
__global__ __launch_bounds__(256)
void build_d_kernel(const float* __restrict__ x,
                    unsigned short* __restrict__ Dhi, unsigned short* __restrict__ Dlo)
{
  int id = blockIdx.x * 256 + threadIdx.x;     // [0, 8192*128)
  int b = id >> 7, c = id & 127;
  float val;
  if (c < 25)             val = x[(size_t)b * INSZ + c];
  else if (c < 100)       val = x[(size_t)b * INSZ + 26 + (c - 25)];
  else                    val = 0.0f;          // c==100 -> iter 0 == 0.0f
  unsigned short hi, lo; split2(val, hi, lo);
  Dhi[id] = hi; Dlo[id] = lo;
}

// ---------------------------------------------------------------------------
// GEMM body: C[M=8192 x N] = A[M x K] @ B(n-major)[N x K], split-bf16, 3-prod.
// 128x128 tile, BK=64, 4 waves (2x2), 4x4 16x16x32 frags/wave.
// EPI 0: tanh(acc + bias[n]) -> split store  (grid role = 256 blocks)
// EPI 1: acc * (1 - h^2)     -> split store  (256 blocks)
// EPI 2: grad store n<101                     (64 blocks)
// ---------------------------------------------------------------------------
template<int EPI>
__device__ __forceinline__ void gemm_body(const GArgs g, short* smem, int id)
{
  short* As_hi = smem;
  short* As_lo = smem + 8192;
  short* Bs_hi = smem + 16384;
  short* Bs_lo = smem + 24576;

  const int t = threadIdx.x;
  const int w = t >> 6;
  const int lane = t & 63;
  const int l15 = lane & 15, l4 = lane >> 4;
  const int bm = (EPI == 2) ? id : (id & 63);
  const int bn = (EPI == 2) ? 0  : (id >> 6);
  const int wm = (w >> 1) * 64, wn = (w & 1) * 64;
  const int K = g.K;
  f32x4 acc[4][4] = {};

  const int sr = t >> 3;   // 0..31
  const int ss = t & 7;    // 16B slot within 128B row

  for (int kc = 0; kc < K; kc += 64) {
    __syncthreads();
#pragma unroll
    for (int q = 0; q < 4; ++q) {
      int r = q * 32 + sr;
      int c = ss ^ (r & 7);                          // inverse-swizzled source slot
      size_t ga = (size_t)(bm * 128 + r) * K + kc + c * 8;
      size_t gb = (size_t)(bn * 128 + r) * K + kc + c * 8;
      int ldst = q * 2048 + w * 512;                 // wave-uniform LDS base (shorts)
      gload16(g.Ahi + ga, &As_hi[ldst]);
      gload16(g.Alo + ga, &As_lo[ldst]);
      gload16(g.Bhi + gb, &Bs_hi[ldst]);
      gload16(g.Blo + gb, &Bs_lo[ldst]);
    }
    __syncthreads();
#pragma unroll
    for (int kk = 0; kk < 2; ++kk) {
      short8 ah[4], al[4], bh[4], bl[4];
#pragma unroll
      for (int mi = 0; mi < 4; ++mi) {
        int row = wm + mi * 16 + l15;
        int eoff = row * 64 + (((kk * 4 + l4) ^ (row & 7)) << 3);
        ah[mi] = *(const short8*)&As_hi[eoff];
        al[mi] = *(const short8*)&As_lo[eoff];
      }
#pragma unroll
      for (int ni = 0; ni < 4; ++ni) {
        int row = wn + ni * 16 + l15;
        int eoff = row * 64 + (((kk * 4 + l4) ^ (row & 7)) << 3);
        bh[ni] = *(const short8*)&Bs_hi[eoff];
        bl[ni] = *(const short8*)&Bs_lo[eoff];
      }
#pragma unroll
      for (int mi = 0; mi < 4; ++mi)
#pragma unroll
        for (int ni = 0; ni < 4; ++ni) {
          acc[mi][ni] = __builtin_amdgcn_mfma_f32_16x16x32_bf16(
              __builtin_bit_cast(bf16x8, ah[mi]), __builtin_bit_cast(bf16x8, bh[ni]),
              acc[mi][ni], 0, 0, 0);
          acc[mi][ni] = __builtin_amdgcn_mfma_f32_16x16x32_bf16(
              __builtin_bit_cast(bf16x8, ah[mi]), __builtin_bit_cast(bf16x8, bl[ni]),
              acc[mi][ni], 0, 0, 0);
          acc[mi][ni] = __builtin_amdgcn_mfma_f32_16x16x32_bf16(
              __builtin_bit_cast(bf16x8, al[mi]), __builtin_bit_cast(bf16x8, bh[ni]),
              acc[mi][ni], 0, 0, 0);
        }
    }
  }

  const int gm0 = bm * 128 + wm;
  const int gn0 = bn * 128 + wn;
#pragma unroll
  for (int mi = 0; mi < 4; ++mi) {
#pragma unroll
    for (int ni = 0; ni < 4; ++ni) {
      int n = gn0 + ni * 16 + l15;
#pragma unroll
      for (int r = 0; r < 4; ++r) {
        int m = gm0 + mi * 16 + l4 * 4 + r;
        float v = acc[mi][ni][r];
        if constexpr (EPI == 0) {
          float h = fast_tanh(v + g.bias[n]);
          unsigned short hi, lo; split2(h, hi, lo);
          size_t idx = (size_t)m * UNITS + n;
          g.Ohi[idx] = hi; g.Olo[idx] = lo;
        } else if constexpr (EPI == 1) {
          size_t idx = (size_t)m * UNITS + n;
          float h = b2f(g.Hhi[idx]) + b2f(g.Hlo[idx]);
          float u = v * (1.0f - h * h);
          unsigned short hi, lo; split2(u, hi, lo);
          g.Ohi[idx] = hi; g.Olo[idx] = lo;
        } else {
          if (n < GRAD_COLS)
            g.Og[((size_t)m * NITER + g.iter) * GRAD_COLS + n] = v;
        }
      }
    }
  }
}

template<int EA, int EB>
__global__ __launch_bounds__(256, 2)
void paired_kernel(GArgs A, GArgs B, int nA) {
  __shared__ short smem[32768];
  int id = blockIdx.x;
  if (id < nA) gemm_body<EA>(A, smem, id);
  else         gemm_body<EB>(B, smem, id - nA);
}

template<int E>
__global__ __launch_bounds__(256, 2)
void solo_kernel(GArgs A) {
  __shared__ short smem[32768];
  gemm_body<E>(A, smem, blockIdx.x);
}

// ---------------------------------------------------------------------------
// dot (w[:,i] = H3.W4 + b4) + U3 = (1-H3^2)*W4 + build D for iter i+1
// one wave per row; after the 64-lane reduction every lane holds the dot.
// ---------------------------------------------------------------------------
__global__ __launch_bounds__(256)
void dot_bd_kernel(const unsigned short* __restrict__ H3hi, const unsigned short* __restrict__ H3lo,
                   const float* __restrict__ W4, const float* __restrict__ b4,
                   const float* __restrict__ x, float* __restrict__ w_out,
                   unsigned short* __restrict__ Uhi, unsigned short* __restrict__ Ulo,
                   unsigned short* __restrict__ Dhi, unsigned short* __restrict__ Dlo,
                   int iter, int buildD)
{
  int w = threadIdx.x >> 6, lane = threadIdx.x & 63;
  int b = blockIdx.x * 4 + w;
  size_t base = (size_t)b * UNITS + lane * 8;
  short8 vhi = *(const short8*)&H3hi[base];
  short8 vlo = *(const short8*)&H3lo[base];
  float dot = 0.0f;
  short8 ohi, olo;
#pragma unroll
  for (int j = 0; j < 8; ++j) {
    float h = b2f((unsigned short)vhi[j]) + b2f((unsigned short)vlo[j]);
    float g = W4[lane * 8 + j];
    dot += h * g;
    float u = (1.0f - h * h) * g;
    unsigned short hi, lo; split2(u, hi, lo);
    ohi[j] = (short)hi; olo[j] = (short)lo;
  }
  *(short8*)&Uhi[base] = ohi;
  *(short8*)&Ulo[base] = olo;
#pragma unroll
  for (int off = 1; off < 64; off <<= 1) dot += __shfl_xor(dot, off);
  float wv = dot + b4[0];
  if (lane == 0) w_out[(size_t)b * NITER + iter] = wv;

  if (buildD) {
    int jn = iter + 1;                       // building D for iteration jn
#pragma unroll
    for (int cc = 0; cc < 2; ++cc) {
      int c = lane + cc * 64;
      float val;
      if (c < 25 - jn)        val = x[(size_t)b * INSZ + jn + c];
      else if (c < 24)        val = w_out[(size_t)b * NITER + (c - (25 - jn))];
      else if (c == 24)       val = wv;      // w[:, jn-1] just computed, in-register
      else if (c < 100)       val = x[(size_t)b * INSZ + 26 + 3 * jn + (c - 25)];
      else if (c == 100)      val = (float)jn;
      else                    val = 0.0f;
      unsigned short hi, lo; split2(val, hi, lo);
      size_t idx = (size_t)b * KPAD + c;
      Dhi[idx] = hi; Dlo[idx] = lo;
    }
  }
}

// ---------------------------------------------------------------------------
extern "C" void kernel_launch(void* const* d_in, const int* in_sizes, int n_in,
                              void* d_out, int out_size, void* d_ws, size_t ws_size,
                              hipStream_t stream) {
  const float* x  = (const float*)d_in[0];
  const float* W0 = (const float*)d_in[1];
  const float* b0 = (const float*)d_in[2];
  const float* W1 = (const float*)d_in[3];
  const float* b1 = (const float*)d_in[4];
  const float* W2 = (const float*)d_in[5];
  const float* b2 = (const float*)d_in[6];
  const float* W3 = (const float*)d_in[7];
  const float* b3 = (const float*)d_in[8];
  const float* W4 = (const float*)d_in[9];
  const float* b4 = (const float*)d_in[10];

  float* w_out    = (float*)d_out;                              // (8192, 25)
  float* grad_out = (float*)d_out + (size_t)B_ROWS * NITER;     // (8192, 25, 101)

  char* p = (char*)d_ws;
  auto alloc = [&](size_t elems) { unsigned short* r = (unsigned short*)p; p += elems * 2; return r; };

  unsigned short* TW0hi = alloc(512 * KPAD); unsigned short* TW0lo = alloc(512 * KPAD);
  unsigned short* TW1hi = alloc(512 * 512);  unsigned short* TW1lo = alloc(512 * 512);
  unsigned short* TW2hi = alloc(512 * 512);  unsigned short* TW2lo = alloc(512 * 512);
  unsigned short* TW3hi = alloc(512 * 512);  unsigned short* TW3lo = alloc(512 * 512);
  unsigned short* CW0hi = alloc(KPAD * 512); unsigned short* CW0lo = alloc(KPAD * 512);
  unsigned short* CW1hi = alloc(512 * 512);  unsigned short* CW1lo = alloc(512 * 512);
  unsigned short* CW2hi = alloc(512 * 512);  unsigned short* CW2lo = alloc(512 * 512);
  unsigned short* CW3hi = alloc(512 * 512);  unsigned short* CW3lo = alloc(512 * 512);

  unsigned short* Dhi = alloc((size_t)B_ROWS * KPAD);
  unsigned short* Dlo = alloc((size_t)B_ROWS * KPAD);

  unsigned short *Hhi[2][4], *Hlo[2][4];
  for (int par = 0; par < 2; ++par)
    for (int l = 0; l < 4; ++l) {
      Hhi[par][l] = alloc((size_t)B_ROWS * UNITS);
      Hlo[par][l] = alloc((size_t)B_ROWS * UNITS);
    }
  unsigned short* Uahi = alloc((size_t)B_ROWS * UNITS); unsigned short* Ualo = alloc((size_t)B_ROWS * UNITS);
  unsigned short* Ubhi = alloc((size_t)B_ROWS * UNITS); unsigned short* Ublo = alloc((size_t)B_ROWS * UNITS);

  prep_kernel<<<1024, 256, 0, stream>>>(W0, W1, W2, W3,
      TW0hi, TW0lo, TW1hi, TW1lo, TW2hi, TW2lo, TW3hi, TW3lo,
      CW0hi, CW0lo, CW1hi, CW1lo, CW2hi, CW2lo, CW3hi, CW3lo);

  build_d_kernel<<<4096, 256, 0, stream>>>(x, Dhi, Dlo);

  // forward chain for iteration 0 (parity 0)
  {
    GArgs f0 = {Dhi, Dlo, TW0hi, TW0lo, KPAD, b0, nullptr, nullptr, Hhi[0][0], Hlo[0][0], nullptr, 0};
    GArgs f1 = {Hhi[0][0], Hlo[0][0], TW1hi, TW1lo, 512, b1, nullptr, nullptr, Hhi[0][1], Hlo[0][1], nullptr, 0};
    GArgs f2 = {Hhi[0][1], Hlo[0][1], TW2hi, TW2lo, 512, b2, nullptr, nullptr, Hhi[0][2], Hlo[0][2], nullptr, 0};
    GArgs f3 = {Hhi[0][2], Hlo[0][2], TW3hi, TW3lo, 512, b3, nullptr, nullptr, Hhi[0][3], Hlo[0][3], nullptr, 0};
    solo_kernel<0><<<256, 256, 0, stream>>>(f0);
    solo_kernel<0><<<256, 256, 0, stream>>>(f1);
    solo_kernel<0><<<256, 256, 0, stream>>>(f2);
    solo_kernel<0><<<256, 256, 0, stream>>>(f3);
  }

  for (int i = 0; i < NITER; ++i) {
    int pp = i & 1, q = pp ^ 1;
    bool more = (i < NITER - 1);

    dot_bd_kernel<<<2048, 256, 0, stream>>>(Hhi[pp][3], Hlo[pp][3], W4, b4, x, w_out,
                                            Uahi, Ualo, Dhi, Dlo, i, more ? 1 : 0);

    GArgs bw3 = {Uahi, Ualo, CW3hi, CW3lo, 512, nullptr, Hhi[pp][2], Hlo[pp][2], Ubhi, Ublo, nullptr, 0};
    GArgs bw2 = {Ubhi, Ublo, CW2hi, CW2lo, 512, nullptr, Hhi[pp][1], Hlo[pp][1], Uahi, Ualo, nullptr, 0};
    GArgs bw1 = {Uahi, Ualo, CW1hi, CW1lo, 512, nullptr, Hhi[pp][0], Hlo[pp][0], Ubhi, Ublo, nullptr, 0};
    GArgs gr0 = {Ubhi, Ublo, CW0hi, CW0lo, 512, nullptr, nullptr, nullptr, nullptr, nullptr, grad_out, i};

    if (more) {
      GArgs f0 = {Dhi, Dlo, TW0hi, TW0lo, KPAD, b0, nullptr, nullptr, Hhi[q][0], Hlo[q][0], nullptr, 0};
      GArgs f1 = {Hhi[q][0], Hlo[q][0], TW1hi, TW1lo, 512, b1, nullptr, nullptr, Hhi[q][1], Hlo[q][1], nullptr, 0};
      GArgs f2 = {Hhi[q][1], Hlo[q][1], TW2hi, TW2lo, 512, b2, nullptr, nullptr, Hhi[q][2], Hlo[q][2], nullptr, 0};
      GArgs f3 = {Hhi[q][2], Hlo[q][2], TW3hi, TW3lo, 512, b3, nullptr, nullptr, Hhi[q][3], Hlo[q][3], nullptr, 0};
      paired_kernel<1, 0><<<512, 256, 0, stream>>>(bw3, f0, 256);
      paired_kernel<1, 0><<<512, 256, 0, stream>>>(bw2, f1, 256);
      paired_kernel<1, 0><<<512, 256, 0, stream>>>(bw1, f2, 256);
      paired_kernel<2, 0><<<320, 256, 0, stream>>>(gr0, f3, 64);
    } else {
      solo_kernel<1><<<256, 256, 0, stream>>>(bw3);
      solo_kernel<1><<<256, 256, 0, stream>>>(bw2);
      solo_kernel<1><<<256, 256, 0, stream>>>(bw1);
      solo_kernel<2><<<64, 256, 0, stream>>>(gr0);
    }
  }

  (void)in_sizes; (void)n_in; (void)out_size; (void)ws_size;
}

// Round 3
// 2550.116 us; speedup vs baseline: 1.6651x; 1.3255x over previous
//
#include <hip/hip_runtime.h>

#define B_ROWS 8192
#define UNITS 512
#define NITER 25
#define INSZ 176
#define KPAD 128
#define GRAD_COLS 101

typedef __attribute__((ext_vector_type(8))) short short8;
typedef __attribute__((ext_vector_type(4))) float f32x4;
typedef __attribute__((ext_vector_type(8))) _Float16 half8;

__device__ __forceinline__ unsigned short f2h_bits(float f) {
  _Float16 h = (_Float16)f;
  return __builtin_bit_cast(unsigned short, h);
}
__device__ __forceinline__ float h2f_bits(unsigned short b) {
  return (float)__builtin_bit_cast(_Float16, b);
}
// weight split: hi = fp16(v), lo = fp16((v - hi) * 2048)  [lo kept in normal range]
__device__ __forceinline__ void splitw(float v, unsigned short& hi, unsigned short& lo) {
  _Float16 h = (_Float16)v;
  float r = v - (float)h;
  hi = __builtin_bit_cast(unsigned short, h);
  lo = f2h_bits(r * 2048.0f);
}
__device__ __forceinline__ float fast_tanh(float x) {
  float e = __expf(2.0f * x);
  return 1.0f - 2.0f / (e + 1.0f);
}

typedef __attribute__((address_space(3))) unsigned int lds_u32;
typedef __attribute__((address_space(1))) const unsigned int glb_u32;
__device__ __forceinline__ void gload16(const void* g, void* l) {
  __builtin_amdgcn_global_load_lds((glb_u32*)g, (lds_u32*)l, 16, 0, 0);
}

struct GArgs {
  const unsigned short *A;            // activations, single fp16 plane, M x K
  const unsigned short *Bhi, *Blo;    // weights, split fp16 planes, N x K (n-major)
  int K;
  const float* bias;
  const unsigned short *Hh;           // fwd activations for EPI1
  unsigned short *Oh;                 // output plane (fp16)
  float* Og;                          // grad output (EPI2)
  int iter;
};

// ---------------------------------------------------------------------------
// Weight prep: split-fp16 planes, n-major layouts, zero-padded.
// ---------------------------------------------------------------------------
__global__ __launch_bounds__(256)
void prep_kernel(const float* __restrict__ W0, const float* __restrict__ W1,
                 const float* __restrict__ W2, const float* __restrict__ W3,
                 unsigned short* TW0hi, unsigned short* TW0lo,
                 unsigned short* TW1hi, unsigned short* TW1lo,
                 unsigned short* TW2hi, unsigned short* TW2lo,
                 unsigned short* TW3hi, unsigned short* TW3lo,
                 unsigned short* CW0hi, unsigned short* CW0lo,
                 unsigned short* CW1hi, unsigned short* CW1lo,
                 unsigned short* CW2hi, unsigned short* CW2lo,
                 unsigned short* CW3hi, unsigned short* CW3lo)
{
  int id = blockIdx.x * 256 + threadIdx.x;
  unsigned short hi, lo;
  if (id < 512 * KPAD) {
    int n = id >> 7, k = id & (KPAD - 1);
    float v = (k < 101) ? W0[(size_t)k * 512 + n] : 0.0f;
    splitw(v, hi, lo); TW0hi[id] = hi; TW0lo[id] = lo;
    int n2 = id >> 9, k2 = id & 511;
    float v2 = (n2 < 101) ? W0[(size_t)n2 * 512 + k2] : 0.0f;
    splitw(v2, hi, lo); CW0hi[id] = hi; CW0lo[id] = lo;
  }
  {
    int n = id >> 9, k = id & 511;
    float t;
    t = W1[(size_t)k * 512 + n]; splitw(t, hi, lo); TW1hi[id] = hi; TW1lo[id] = lo;
    t = W2[(size_t)k * 512 + n]; splitw(t, hi, lo); TW2hi[id] = hi; TW2lo[id] = lo;
    t = W3[(size_t)k * 512 + n]; splitw(t, hi, lo); TW3hi[id] = hi; TW3lo[id] = lo;
    t = W1[id]; splitw(t, hi, lo); CW1hi[id] = hi; CW1lo[id] = lo;
    t = W2[id]; splitw(t, hi, lo); CW2hi[id] = hi; CW2lo[id] = lo;
    t = W3[id]; splitw(t, hi, lo); CW3hi[id] = hi; CW3lo[id] = lo;
  }
}

// ---------------------------------------------------------------------------
// Initial build D_0 (8192 x 128, single fp16 plane), zero-padded cols 101..127
// ---------------------------------------------------------------------------
__global__ __launch_bounds__(256)
void build_d_kernel(const float* __restrict__ x, unsigned short* __restrict__ D)
{
  int id = blockIdx.x * 256 + threadIdx.x;     // [0, 8192*128)
  int b = id >> 7, c = id & 127;
  float val;
  if (c < 25)             val = x[(size_t)b * INSZ + c];
  else if (c < 100)       val = x[(size_t)b * INSZ + 26 + (c - 25)];
  else                    val = 0.0f;          // c==100 -> iter 0 == 0.0f
  D[id] = f2h_bits(val);
}

// ---------------------------------------------------------------------------
// GEMM body: C[M x N] = A[M x K] @ B(n-major)[N x K], fp16, 2-product dual-acc.
// 128x128 tile, BK=64, 4 waves (2x2), 4x4 16x16x32 frags/wave.
// ---------------------------------------------------------------------------
template<int EPI>
__device__ __forceinline__ void gemm_body(const GArgs g, short* smem, int id)
{
  short* As    = smem;            // 128 x 64 halves
  short* Bs_hi = smem + 8192;
  short* Bs_lo = smem + 16384;

  const int t = threadIdx.x;
  const int w = t >> 6;
  const int lane = t & 63;
  const int l15 = lane & 15, l4 = lane >> 4;
  const int bm = (EPI == 2) ? id : (id & 63);
  const int bn = (EPI == 2) ? 0  : (id >> 6);
  const int wm = (w >> 1) * 64, wn = (w & 1) * 64;
  const int K = g.K;
  f32x4 accH[4][4] = {};
  f32x4 accL[4][4] = {};

  const int sr = t >> 3;   // 0..31
  const int ss = t & 7;    // 16B slot within 128B row

  for (int kc = 0; kc < K; kc += 64) {
    __syncthreads();
#pragma unroll
    for (int q = 0; q < 4; ++q) {
      int r = q * 32 + sr;
      int c = ss ^ (r & 7);                          // inverse-swizzled source slot
      size_t ga = (size_t)(bm * 128 + r) * K + kc + c * 8;
      size_t gb = (size_t)(bn * 128 + r) * K + kc + c * 8;
      int ldst = q * 2048 + w * 512;                 // wave-uniform LDS base (shorts)
      gload16(g.A   + ga, &As[ldst]);
      gload16(g.Bhi + gb, &Bs_hi[ldst]);
      gload16(g.Blo + gb, &Bs_lo[ldst]);
    }
    __syncthreads();
#pragma unroll
    for (int kk = 0; kk < 2; ++kk) {
      short8 av[4], bh[4], bl[4];
#pragma unroll
      for (int mi = 0; mi < 4; ++mi) {
        int row = wm + mi * 16 + l15;
        int eoff = row * 64 + (((kk * 4 + l4) ^ (row & 7)) << 3);
        av[mi] = *(const short8*)&As[eoff];
      }
#pragma unroll
      for (int ni = 0; ni < 4; ++ni) {
        int row = wn + ni * 16 + l15;
        int eoff = row * 64 + (((kk * 4 + l4) ^ (row & 7)) << 3);
        bh[ni] = *(const short8*)&Bs_hi[eoff];
        bl[ni] = *(const short8*)&Bs_lo[eoff];
      }
#pragma unroll
      for (int mi = 0; mi < 4; ++mi)
#pragma unroll
        for (int ni = 0; ni < 4; ++ni) {
          accH[mi][ni] = __builtin_amdgcn_mfma_f32_16x16x32_f16(
              __builtin_bit_cast(half8, av[mi]), __builtin_bit_cast(half8, bh[ni]),
              accH[mi][ni], 0, 0, 0);
          accL[mi][ni] = __builtin_amdgcn_mfma_f32_16x16x32_f16(
              __builtin_bit_cast(half8, av[mi]), __builtin_bit_cast(half8, bl[ni]),
              accL[mi][ni], 0, 0, 0);
        }
    }
  }

  const int gm0 = bm * 128 + wm;
  const int gn0 = bn * 128 + wn;
#pragma unroll
  for (int mi = 0; mi < 4; ++mi) {
#pragma unroll
    for (int ni = 0; ni < 4; ++ni) {
      int n = gn0 + ni * 16 + l15;
#pragma unroll
      for (int r = 0; r < 4; ++r) {
        int m = gm0 + mi * 16 + l4 * 4 + r;
        float v = accH[mi][ni][r] + accL[mi][ni][r] * (1.0f / 2048.0f);
        if constexpr (EPI == 0) {
          float h = fast_tanh(v + g.bias[n]);
          g.Oh[(size_t)m * UNITS + n] = f2h_bits(h);
        } else if constexpr (EPI == 1) {
          size_t idx = (size_t)m * UNITS + n;
          float h = h2f_bits(g.Hh[idx]);
          g.Oh[idx] = f2h_bits(v * (1.0f - h * h));
        } else {
          if (n < GRAD_COLS)
            g.Og[((size_t)m * NITER + g.iter) * GRAD_COLS + n] = v;
        }
      }
    }
  }
}

template<int EA, int EB>
__global__ __launch_bounds__(256, 2)
void paired_kernel(GArgs A, GArgs B, int nA) {
  __shared__ short smem[24576];
  int id = blockIdx.x;
  if (id < nA) gemm_body<EA>(A, smem, id);
  else         gemm_body<EB>(B, smem, id - nA);
}

template<int E>
__global__ __launch_bounds__(256, 2)
void solo_kernel(GArgs A) {
  __shared__ short smem[24576];
  gemm_body<E>(A, smem, blockIdx.x);
}

// ---------------------------------------------------------------------------
// dot (w[:,i] = H3.W4 + b4) + U3 = (1-H3^2)*W4 + build D for iter i+1
// ---------------------------------------------------------------------------
__global__ __launch_bounds__(256)
void dot_bd_kernel(const unsigned short* __restrict__ H3,
                   const float* __restrict__ W4, const float* __restrict__ b4,
                   const float* __restrict__ x, float* __restrict__ w_out,
                   unsigned short* __restrict__ U,
                   unsigned short* __restrict__ D,
                   int iter, int buildD)
{
  int w = threadIdx.x >> 6, lane = threadIdx.x & 63;
  int b = blockIdx.x * 4 + w;
  size_t base = (size_t)b * UNITS + lane * 8;
  short8 vh = *(const short8*)&H3[base];
  float dot = 0.0f;
  short8 ou;
#pragma unroll
  for (int j = 0; j < 8; ++j) {
    float h = h2f_bits((unsigned short)vh[j]);
    float g = W4[lane * 8 + j];
    dot += h * g;
    ou[j] = (short)f2h_bits((1.0f - h * h) * g);
  }
  *(short8*)&U[base] = ou;
#pragma unroll
  for (int off = 1; off < 64; off <<= 1) dot += __shfl_xor(dot, off);
  float wv = dot + b4[0];
  if (lane == 0) w_out[(size_t)b * NITER + iter] = wv;

  if (buildD) {
    int jn = iter + 1;
#pragma unroll
    for (int cc = 0; cc < 2; ++cc) {
      int c = lane + cc * 64;
      float val;
      if (c < 25 - jn)        val = x[(size_t)b * INSZ + jn + c];
      else if (c < 24)        val = w_out[(size_t)b * NITER + (c - (25 - jn))];
      else if (c == 24)       val = wv;      // w[:, jn-1] just computed, in-register
      else if (c < 100)       val = x[(size_t)b * INSZ + 26 + 3 * jn + (c - 25)];
      else if (c == 100)      val = (float)jn;
      else                    val = 0.0f;
      D[(size_t)b * KPAD + c] = f2h_bits(val);
    }
  }
}

// ---------------------------------------------------------------------------
extern "C" void kernel_launch(void* const* d_in, const int* in_sizes, int n_in,
                              void* d_out, int out_size, void* d_ws, size_t ws_size,
                              hipStream_t stream) {
  const float* x  = (const float*)d_in[0];
  const float* W0 = (const float*)d_in[1];
  const float* b0 = (const float*)d_in[2];
  const float* W1 = (const float*)d_in[3];
  const float* b1 = (const float*)d_in[4];
  const float* W2 = (const float*)d_in[5];
  const float* b2 = (const float*)d_in[6];
  const float* W3 = (const float*)d_in[7];
  const float* b3 = (const float*)d_in[8];
  const float* W4 = (const float*)d_in[9];
  const float* b4 = (const float*)d_in[10];

  float* w_out    = (float*)d_out;                              // (8192, 25)
  float* grad_out = (float*)d_out + (size_t)B_ROWS * NITER;     // (8192, 25, 101)

  char* p = (char*)d_ws;
  auto alloc = [&](size_t elems) { unsigned short* r = (unsigned short*)p; p += elems * 2; return r; };

  unsigned short* TW0hi = alloc(512 * KPAD); unsigned short* TW0lo = alloc(512 * KPAD);
  unsigned short* TW1hi = alloc(512 * 512);  unsigned short* TW1lo = alloc(512 * 512);
  unsigned short* TW2hi = alloc(512 * 512);  unsigned short* TW2lo = alloc(512 * 512);
  unsigned short* TW3hi = alloc(512 * 512);  unsigned short* TW3lo = alloc(512 * 512);
  unsigned short* CW0hi = alloc(KPAD * 512); unsigned short* CW0lo = alloc(KPAD * 512);
  unsigned short* CW1hi = alloc(512 * 512);  unsigned short* CW1lo = alloc(512 * 512);
  unsigned short* CW2hi = alloc(512 * 512);  unsigned short* CW2lo = alloc(512 * 512);
  unsigned short* CW3hi = alloc(512 * 512);  unsigned short* CW3lo = alloc(512 * 512);

  unsigned short* D = alloc((size_t)B_ROWS * KPAD);

  unsigned short *H[2][4];
  for (int par = 0; par < 2; ++par)
    for (int l = 0; l < 4; ++l)
      H[par][l] = alloc((size_t)B_ROWS * UNITS);
  unsigned short* Ua = alloc((size_t)B_ROWS * UNITS);
  unsigned short* Ub = alloc((size_t)B_ROWS * UNITS);

  prep_kernel<<<1024, 256, 0, stream>>>(W0, W1, W2, W3,
      TW0hi, TW0lo, TW1hi, TW1lo, TW2hi, TW2lo, TW3hi, TW3lo,
      CW0hi, CW0lo, CW1hi, CW1lo, CW2hi, CW2lo, CW3hi, CW3lo);

  build_d_kernel<<<4096, 256, 0, stream>>>(x, D);

  // forward chain for iteration 0 (parity 0)
  {
    GArgs f0 = {D, TW0hi, TW0lo, KPAD, b0, nullptr, H[0][0], nullptr, 0};
    GArgs f1 = {H[0][0], TW1hi, TW1lo, 512, b1, nullptr, H[0][1], nullptr, 0};
    GArgs f2 = {H[0][1], TW2hi, TW2lo, 512, b2, nullptr, H[0][2], nullptr, 0};
    GArgs f3 = {H[0][2], TW3hi, TW3lo, 512, b3, nullptr, H[0][3], nullptr, 0};
    solo_kernel<0><<<256, 256, 0, stream>>>(f0);
    solo_kernel<0><<<256, 256, 0, stream>>>(f1);
    solo_kernel<0><<<256, 256, 0, stream>>>(f2);
    solo_kernel<0><<<256, 256, 0, stream>>>(f3);
  }

  for (int i = 0; i < NITER; ++i) {
    int pp = i & 1, q = pp ^ 1;
    bool more = (i < NITER - 1);

    dot_bd_kernel<<<2048, 256, 0, stream>>>(H[pp][3], W4, b4, x, w_out,
                                            Ua, D, i, more ? 1 : 0);

    GArgs bw3 = {Ua, CW3hi, CW3lo, 512, nullptr, H[pp][2], Ub, nullptr, 0};
    GArgs bw2 = {Ub, CW2hi, CW2lo, 512, nullptr, H[pp][1], Ua, nullptr, 0};
    GArgs bw1 = {Ua, CW1hi, CW1lo, 512, nullptr, H[pp][0], Ub, nullptr, 0};
    GArgs gr0 = {Ub, CW0hi, CW0lo, 512, nullptr, nullptr, nullptr, grad_out, i};

    if (more) {
      GArgs f0 = {D, TW0hi, TW0lo, KPAD, b0, nullptr, H[q][0], nullptr, 0};
      GArgs f1 = {H[q][0], TW1hi, TW1lo, 512, b1, nullptr, H[q][1], nullptr, 0};
      GArgs f2 = {H[q][1], TW2hi, TW2lo, 512, b2, nullptr, H[q][2], nullptr, 0};
      GArgs f3 = {H[q][2], TW3hi, TW3lo, 512, b3, nullptr, H[q][3], nullptr, 0};
      paired_kernel<1, 0><<<512, 256, 0, stream>>>(bw3, f0, 256);
      paired_kernel<1, 0><<<512, 256, 0, stream>>>(bw2, f1, 256);
      paired_kernel<1, 0><<<512, 256, 0, stream>>>(bw1, f2, 256);
      paired_kernel<2, 0><<<320, 256, 0, stream>>>(gr0, f3, 64);
    } else {
      solo_kernel<1><<<256, 256, 0, stream>>>(bw3);
      solo_kernel<1><<<256, 256, 0, stream>>>(bw2);
      solo_kernel<1><<<256, 256, 0, stream>>>(bw1);
      solo_kernel<2><<<64, 256, 0, stream>>>(gr0);
    }
  }

  (void)in_sizes; (void)n_in; (void)out_size; (void)ws_size;
}

// Round 5
// 2001.963 us; speedup vs baseline: 2.1211x; 1.2738x over previous
//
#include <hip/hip_runtime.h>

#define B_ROWS 8192
#define UNITS 512
#define NITER 25
#define INSZ 176
#define KPAD 128
#define GRAD_COLS 101

typedef __attribute__((ext_vector_type(8))) short short8;
typedef __attribute__((ext_vector_type(4))) float f32x4;
typedef __attribute__((ext_vector_type(8))) _Float16 half8;

__device__ __forceinline__ unsigned short f2h_bits(float f) {
  _Float16 h = (_Float16)f;
  return __builtin_bit_cast(unsigned short, h);
}
__device__ __forceinline__ float h2f_bits(unsigned short b) {
  return (float)__builtin_bit_cast(_Float16, b);
}
__device__ __forceinline__ float fast_tanh(float x) {
  float e = __expf(2.0f * x);
  return 1.0f - 2.0f / (e + 1.0f);
}

typedef __attribute__((address_space(3))) unsigned int lds_u32;
typedef __attribute__((address_space(1))) const unsigned int glb_u32;
__device__ __forceinline__ void gload16(const void* g, void* l) {
  __builtin_amdgcn_global_load_lds((glb_u32*)g, (lds_u32*)l, 16, 0, 0);
}

struct GArgs {
  const unsigned short *A;            // activations, fp16 plane, M x K
  const unsigned short *B;            // weights, fp16 plane, N x K (n-major)
  int K;
  const float* bias;
  const unsigned short *Hh;           // fwd activations for EPI1
  unsigned short *Oh;                 // output plane (fp16)
  float* Og;                          // grad output (EPI2)
  int iter;
};

// ---------------------------------------------------------------------------
// Weight prep: fp16 planes, n-major layouts, zero-padded.
// ---------------------------------------------------------------------------
__global__ __launch_bounds__(256)
void prep_kernel(const float* __restrict__ W0, const float* __restrict__ W1,
                 const float* __restrict__ W2, const float* __restrict__ W3,
                 unsigned short* TW0, unsigned short* TW1,
                 unsigned short* TW2, unsigned short* TW3,
                 unsigned short* CW0, unsigned short* CW1,
                 unsigned short* CW2, unsigned short* CW3)
{
  int id = blockIdx.x * 256 + threadIdx.x;
  if (id < 512 * KPAD) {
    int n = id >> 7, k = id & (KPAD - 1);
    TW0[id] = f2h_bits((k < 101) ? W0[(size_t)k * 512 + n] : 0.0f);
    int n2 = id >> 9, k2 = id & 511;
    CW0[id] = f2h_bits((n2 < 101) ? W0[(size_t)n2 * 512 + k2] : 0.0f);
  }
  {
    int n = id >> 9, k = id & 511;
    TW1[id] = f2h_bits(W1[(size_t)k * 512 + n]);
    TW2[id] = f2h_bits(W2[(size_t)k * 512 + n]);
    TW3[id] = f2h_bits(W3[(size_t)k * 512 + n]);
    CW1[id] = f2h_bits(W1[id]);
    CW2[id] = f2h_bits(W2[id]);
    CW3[id] = f2h_bits(W3[id]);
  }
}

// ---------------------------------------------------------------------------
// Initial build D_0 (8192 x 128, fp16), zero-padded cols 101..127
// ---------------------------------------------------------------------------
__global__ __launch_bounds__(256)
void build_d_kernel(const float* __restrict__ x, unsigned short* __restrict__ D)
{
  int id = blockIdx.x * 256 + threadIdx.x;     // [0, 8192*128)
  int b = id >> 7, c = id & 127;
  float val;
  if (c < 25)             val = x[(size_t)b * INSZ + c];
  else if (c < 100)       val = x[(size_t)b * INSZ + 26 + (c - 25)];
  else                    val = 0.0f;          // c==100 -> iter 0 == 0.0f
  D[id] = f2h_bits(val);
}

// ---------------------------------------------------------------------------
// GEMM body: C[M x N] = A[M x K] @ B(n-major)[N x K], fp16 single product.
// 128x128 tile, BK=64, double-buffered LDS, 2-phase pipeline:
//   { stage(next) ; compute(cur) ; __syncthreads() }
// stage latency hides under compute; __syncthreads (vmcnt0+lgkmcnt0+barrier)
// is REQUIRED for correctness: a raw s_barrier with only vmcnt(0) lets the
// compiler sink MFMA+lgkmcnt waits past the barrier, so a wave can cross with
// outstanding ds_reads while another wave's stage overwrites the buffer
// (round-4 replay divergence).
// ---------------------------------------------------------------------------
template<int EPI>
__device__ __forceinline__ void gemm_body(const GArgs g, short* smem, int id)
{
  const int t = threadIdx.x;
  const int w = t >> 6;
  const int lane = t & 63;
  const int l15 = lane & 15, l4 = lane >> 4;
  const int bm = (EPI == 2) ? id : (id & 63);
  const int bn = (EPI == 2) ? 0  : (id >> 6);
  const int wm = (w >> 1) * 64, wn = (w & 1) * 64;
  const int K = g.K;
  const int NK = K >> 6;
  f32x4 acc[4][4] = {};

  const int sr = t >> 3;   // 0..31 (row within 32-row round)
  const int ss = t & 7;    // linear 16B slot within 128B row

  // stage K-step ks into buffer buf (A: 8192 shorts, B: 8192 shorts)
  auto stage = [&](int ks, int buf) {
    short* As = smem + buf * 16384;
    short* Bs = As + 8192;
    int kc = ks << 6;
#pragma unroll
    for (int q = 0; q < 4; ++q) {
      int r = q * 32 + sr;
      int c = ss ^ (r & 7);                          // inverse-swizzled source slot
      size_t ga = (size_t)(bm * 128 + r) * K + kc + c * 8;
      size_t gb = (size_t)(bn * 128 + r) * K + kc + c * 8;
      int ldst = q * 2048 + w * 512;                 // wave-uniform LDS base (shorts)
      gload16(g.A + ga, &As[ldst]);
      gload16(g.B + gb, &Bs[ldst]);
    }
  };

  stage(0, 0);
  __syncthreads();

  for (int ks = 0; ks < NK; ++ks) {
    if (ks + 1 < NK) stage(ks + 1, (ks + 1) & 1);
    const short* As = smem + (ks & 1) * 16384;
    const short* Bs = As + 8192;
#pragma unroll
    for (int kk = 0; kk < 2; ++kk) {
      short8 av[4], bh[4];
#pragma unroll
      for (int mi = 0; mi < 4; ++mi) {
        int row = wm + mi * 16 + l15;
        int eoff = row * 64 + (((kk * 4 + l4) ^ (row & 7)) << 3);
        av[mi] = *(const short8*)&As[eoff];
      }
#pragma unroll
      for (int ni = 0; ni < 4; ++ni) {
        int row = wn + ni * 16 + l15;
        int eoff = row * 64 + (((kk * 4 + l4) ^ (row & 7)) << 3);
        bh[ni] = *(const short8*)&Bs[eoff];
      }
#pragma unroll
      for (int mi = 0; mi < 4; ++mi)
#pragma unroll
        for (int ni = 0; ni < 4; ++ni)
          acc[mi][ni] = __builtin_amdgcn_mfma_f32_16x16x32_f16(
              __builtin_bit_cast(half8, av[mi]), __builtin_bit_cast(half8, bh[ni]),
              acc[mi][ni], 0, 0, 0);
    }
    // full sync: drains this wave's staging (overlapped by compute above) AND
    // its ds_reads, then barrier — safe buffer handoff for the next K-step.
    __syncthreads();
  }

  const int gm0 = bm * 128 + wm;
  const int gn0 = bn * 128 + wn;
#pragma unroll
  for (int mi = 0; mi < 4; ++mi) {
#pragma unroll
    for (int ni = 0; ni < 4; ++ni) {
      int n = gn0 + ni * 16 + l15;
#pragma unroll
      for (int r = 0; r < 4; ++r) {
        int m = gm0 + mi * 16 + l4 * 4 + r;
        float v = acc[mi][ni][r];
        if constexpr (EPI == 0) {
          float h = fast_tanh(v + g.bias[n]);
          g.Oh[(size_t)m * UNITS + n] = f2h_bits(h);
        } else if constexpr (EPI == 1) {
          size_t idx = (size_t)m * UNITS + n;
          float h = h2f_bits(g.Hh[idx]);
          g.Oh[idx] = f2h_bits(v * (1.0f - h * h));
        } else {
          if (n < GRAD_COLS)
            g.Og[((size_t)m * NITER + g.iter) * GRAD_COLS + n] = v;
        }
      }
    }
  }
}

template<int EA, int EB>
__global__ __launch_bounds__(256, 2)
void paired_kernel(GArgs A, GArgs B, int nA) {
  __shared__ short smem[32768];        // 2 bufs x (A 8192 + B 8192)
  int id = blockIdx.x;
  if (id < nA) gemm_body<EA>(A, smem, id);
  else         gemm_body<EB>(B, smem, id - nA);
}

template<int E>
__global__ __launch_bounds__(256, 2)
void solo_kernel(GArgs A) {
  __shared__ short smem[32768];
  gemm_body<E>(A, smem, blockIdx.x);
}

// ---------------------------------------------------------------------------
// dot (w[:,i] = H3.W4 + b4) + U3 = (1-H3^2)*W4 + build D for iter i+1
// ---------------------------------------------------------------------------
__global__ __launch_bounds__(256)
void dot_bd_kernel(const unsigned short* __restrict__ H3,
                   const float* __restrict__ W4, const float* __restrict__ b4,
                   const float* __restrict__ x, float* __restrict__ w_out,
                   unsigned short* __restrict__ U,
                   unsigned short* __restrict__ D,
                   int iter, int buildD)
{
  int w = threadIdx.x >> 6, lane = threadIdx.x & 63;
  int b = blockIdx.x * 4 + w;
  size_t base = (size_t)b * UNITS + lane * 8;
  short8 vh = *(const short8*)&H3[base];
  float dot = 0.0f;
  short8 ou;
#pragma unroll
  for (int j = 0; j < 8; ++j) {
    float h = h2f_bits((unsigned short)vh[j]);
    float g = W4[lane * 8 + j];
    dot += h * g;
    ou[j] = (short)f2h_bits((1.0f - h * h) * g);
  }
  *(short8*)&U[base] = ou;
#pragma unroll
  for (int off = 1; off < 64; off <<= 1) dot += __shfl_xor(dot, off);
  float wv = dot + b4[0];
  if (lane == 0) w_out[(size_t)b * NITER + iter] = wv;

  if (buildD) {
    int jn = iter + 1;
#pragma unroll
    for (int cc = 0; cc < 2; ++cc) {
      int c = lane + cc * 64;
      float val;
      if (c < 25 - jn)        val = x[(size_t)b * INSZ + jn + c];
      else if (c < 24)        val = w_out[(size_t)b * NITER + (c - (25 - jn))];
      else if (c == 24)       val = wv;      // w[:, jn-1] just computed, in-register
      else if (c < 100)       val = x[(size_t)b * INSZ + 26 + 3 * jn + (c - 25)];
      else if (c == 100)      val = (float)jn;
      else                    val = 0.0f;
      D[(size_t)b * KPAD + c] = f2h_bits(val);
    }
  }
}

// ---------------------------------------------------------------------------
extern "C" void kernel_launch(void* const* d_in, const int* in_sizes, int n_in,
                              void* d_out, int out_size, void* d_ws, size_t ws_size,
                              hipStream_t stream) {
  const float* x  = (const float*)d_in[0];
  const float* W0 = (const float*)d_in[1];
  const float* b0 = (const float*)d_in[2];
  const float* W1 = (const float*)d_in[3];
  const float* b1 = (const float*)d_in[4];
  const float* W2 = (const float*)d_in[5];
  const float* b2 = (const float*)d_in[6];
  const float* W3 = (const float*)d_in[7];
  const float* b3 = (const float*)d_in[8];
  const float* W4 = (const float*)d_in[9];
  const float* b4 = (const float*)d_in[10];

  float* w_out    = (float*)d_out;                              // (8192, 25)
  float* grad_out = (float*)d_out + (size_t)B_ROWS * NITER;     // (8192, 25, 101)

  char* p = (char*)d_ws;
  auto alloc = [&](size_t elems) { unsigned short* r = (unsigned short*)p; p += elems * 2; return r; };

  unsigned short* TW0 = alloc(512 * KPAD);
  unsigned short* TW1 = alloc(512 * 512);
  unsigned short* TW2 = alloc(512 * 512);
  unsigned short* TW3 = alloc(512 * 512);
  unsigned short* CW0 = alloc(KPAD * 512);
  unsigned short* CW1 = alloc(512 * 512);
  unsigned short* CW2 = alloc(512 * 512);
  unsigned short* CW3 = alloc(512 * 512);

  unsigned short* D = alloc((size_t)B_ROWS * KPAD);

  unsigned short *H[2][4];
  for (int par = 0; par < 2; ++par)
    for (int l = 0; l < 4; ++l)
      H[par][l] = alloc((size_t)B_ROWS * UNITS);
  unsigned short* Ua = alloc((size_t)B_ROWS * UNITS);
  unsigned short* Ub = alloc((size_t)B_ROWS * UNITS);

  prep_kernel<<<1024, 256, 0, stream>>>(W0, W1, W2, W3,
      TW0, TW1, TW2, TW3, CW0, CW1, CW2, CW3);

  build_d_kernel<<<4096, 256, 0, stream>>>(x, D);

  // forward chain for iteration 0 (parity 0)
  {
    GArgs f0 = {D, TW0, KPAD, b0, nullptr, H[0][0], nullptr, 0};
    GArgs f1 = {H[0][0], TW1, 512, b1, nullptr, H[0][1], nullptr, 0};
    GArgs f2 = {H[0][1], TW2, 512, b2, nullptr, H[0][2], nullptr, 0};
    GArgs f3 = {H[0][2], TW3, 512, b3, nullptr, H[0][3], nullptr, 0};
    solo_kernel<0><<<256, 256, 0, stream>>>(f0);
    solo_kernel<0><<<256, 256, 0, stream>>>(f1);
    solo_kernel<0><<<256, 256, 0, stream>>>(f2);
    solo_kernel<0><<<256, 256, 0, stream>>>(f3);
  }

  for (int i = 0; i < NITER; ++i) {
    int pp = i & 1, q = pp ^ 1;
    bool more = (i < NITER - 1);

    dot_bd_kernel<<<2048, 256, 0, stream>>>(H[pp][3], W4, b4, x, w_out,
                                            Ua, D, i, more ? 1 : 0);

    GArgs bw3 = {Ua, CW3, 512, nullptr, H[pp][2], Ub, nullptr, 0};
    GArgs bw2 = {Ub, CW2, 512, nullptr, H[pp][1], Ua, nullptr, 0};
    GArgs bw1 = {Ua, CW1, 512, nullptr, H[pp][0], Ub, nullptr, 0};
    GArgs gr0 = {Ub, CW0, 512, nullptr, nullptr, nullptr, grad_out, i};

    if (more) {
      GArgs f0 = {D, TW0, KPAD, b0, nullptr, H[q][0], nullptr, 0};
      GArgs f1 = {H[q][0], TW1, 512, b1, nullptr, H[q][1], nullptr, 0};
      GArgs f2 = {H[q][1], TW2, 512, b2, nullptr, H[q][2], nullptr, 0};
      GArgs f3 = {H[q][2], TW3, 512, b3, nullptr, H[q][3], nullptr, 0};
      paired_kernel<1, 0><<<512, 256, 0, stream>>>(bw3, f0, 256);
      paired_kernel<1, 0><<<512, 256, 0, stream>>>(bw2, f1, 256);
      paired_kernel<1, 0><<<512, 256, 0, stream>>>(bw1, f2, 256);
      paired_kernel<2, 0><<<320, 256, 0, stream>>>(gr0, f3, 64);
    } else {
      solo_kernel<1><<<256, 256, 0, stream>>>(bw3);
      solo_kernel<1><<<256, 256, 0, stream>>>(bw2);
      solo_kernel<1><<<256, 256, 0, stream>>>(bw1);
      solo_kernel<2><<<64, 256, 0, stream>>>(gr0);
    }
  }

  (void)in_sizes; (void)n_in; (void)out_size; (void)ws_size;
}

// Round 6
// 1961.366 us; speedup vs baseline: 2.1650x; 1.0207x over previous
//
#include <hip/hip_runtime.h>

#define B_ROWS 8192
#define UNITS 512
#define NITER 25
#define INSZ 176
#define KPAD 128
#define GRAD_COLS 101

typedef __attribute__((ext_vector_type(8))) short short8;
typedef __attribute__((ext_vector_type(4))) float f32x4;
typedef __attribute__((ext_vector_type(8))) _Float16 half8;

__device__ __forceinline__ unsigned short f2h_bits(float f) {
  _Float16 h = (_Float16)f;
  return __builtin_bit_cast(unsigned short, h);
}
__device__ __forceinline__ float h2f_bits(unsigned short b) {
  return (float)__builtin_bit_cast(_Float16, b);
}
__device__ __forceinline__ float fast_tanh(float x) {
  float e = __expf(2.0f * x);
  return 1.0f - 2.0f / (e + 1.0f);
}

typedef __attribute__((address_space(3))) unsigned int lds_u32;
typedef __attribute__((address_space(1))) const unsigned int glb_u32;
__device__ __forceinline__ void gload16(const void* g, void* l) {
  __builtin_amdgcn_global_load_lds((glb_u32*)g, (lds_u32*)l, 16, 0, 0);
}

struct GArgs {
  const unsigned short *A;            // activations, fp16 plane, M x K
  const unsigned short *B;            // weights, fp16 plane, N x K (n-major)
  int K;
  const float* bias;
  const unsigned short *Hh;           // fwd activations for EPI1
  unsigned short *Oh;                 // output plane (fp16)
  float* Og;                          // grad output (EPI2)
  int iter;
};

// ---------------------------------------------------------------------------
// Weight prep: fp16 planes, n-major layouts, zero-padded.
// ---------------------------------------------------------------------------
__global__ __launch_bounds__(256)
void prep_kernel(const float* __restrict__ W0, const float* __restrict__ W1,
                 const float* __restrict__ W2, const float* __restrict__ W3,
                 unsigned short* TW0, unsigned short* TW1,
                 unsigned short* TW2, unsigned short* TW3,
                 unsigned short* CW0, unsigned short* CW1,
                 unsigned short* CW2, unsigned short* CW3)
{
  int id = blockIdx.x * 256 + threadIdx.x;
  if (id < 512 * KPAD) {
    int n = id >> 7, k = id & (KPAD - 1);
    TW0[id] = f2h_bits((k < 101) ? W0[(size_t)k * 512 + n] : 0.0f);
    int n2 = id >> 9, k2 = id & 511;
    CW0[id] = f2h_bits((n2 < 101) ? W0[(size_t)n2 * 512 + k2] : 0.0f);
  }
  {
    int n = id >> 9, k = id & 511;
    TW1[id] = f2h_bits(W1[(size_t)k * 512 + n]);
    TW2[id] = f2h_bits(W2[(size_t)k * 512 + n]);
    TW3[id] = f2h_bits(W3[(size_t)k * 512 + n]);
    CW1[id] = f2h_bits(W1[id]);
    CW2[id] = f2h_bits(W2[id]);
    CW3[id] = f2h_bits(W3[id]);
  }
}

// ---------------------------------------------------------------------------
// Initial build D_0 (8192 x 128, fp16), zero-padded cols 101..127
// ---------------------------------------------------------------------------
__global__ __launch_bounds__(256)
void build_d_kernel(const float* __restrict__ x, unsigned short* __restrict__ D)
{
  int id = blockIdx.x * 256 + threadIdx.x;     // [0, 8192*128)
  int b = id >> 7, c = id & 127;
  float val;
  if (c < 25)             val = x[(size_t)b * INSZ + c];
  else if (c < 100)       val = x[(size_t)b * INSZ + 26 + (c - 25)];
  else                    val = 0.0f;          // c==100 -> iter 0 == 0.0f
  D[id] = f2h_bits(val);
}

// ---------------------------------------------------------------------------
// GEMM body: C[M x N] = A[M x K] @ B(n-major)[N x K], fp16 single product.
// 128x128 tile, BK=64, double-buffered LDS, counted-vmcnt 2-barrier pipeline:
//   per K-step: { stage(ks+1)->other buf ; vmcnt(8) [only stage(ks)] ;
//                 barrier ; compute(ks) ; lgkmcnt(0)+sched_barrier ; barrier }
// Staging of ks+1 (8 loads/thread) stays in flight across BOTH barriers and
// the whole compute phase (T4). Buffer lifetime: stage(ks+2) overwrites
// buf[ks&1] only after the trailing barrier, which each wave reaches only
// after its own lgkmcnt(0) (all reads of buf[ks&1] retired). Last tile uses
// vmcnt(0) (nothing new in flight, vmcnt(8) would not wait).
// XCD swizzle: the 4 bn-blocks sharing an A-panel get the same id%8 (same
// XCD) -> A-panel HBM fetch once per XCD instead of 4x.
// ---------------------------------------------------------------------------
template<int EPI>
__device__ __forceinline__ void gemm_body(const GArgs g, short* smem, int id)
{
  const int t = threadIdx.x;
  const int w = t >> 6;
  const int lane = t & 63;
  const int l15 = lane & 15, l4 = lane >> 4;
  const int bm = (EPI == 2) ? id : ((id & 7) | ((id >> 5) << 3));
  const int bn = (EPI == 2) ? 0  : ((id >> 3) & 3);
  const int wm = (w >> 1) * 64, wn = (w & 1) * 64;
  const int K = g.K;
  const int NK = K >> 6;
  f32x4 acc[4][4] = {};

  const int sr = t >> 3;   // 0..31 (row within 32-row round)
  const int ss = t & 7;    // linear 16B slot within 128B row

  // stage K-step ks into buffer buf (A: 8192 shorts, B: 8192 shorts)
  // 8 global_load_lds per thread (4 q x 2 operands)
  auto stage = [&](int ks, int buf) {
    short* As = smem + buf * 16384;
    short* Bs = As + 8192;
    int kc = ks << 6;
#pragma unroll
    for (int q = 0; q < 4; ++q) {
      int r = q * 32 + sr;
      int c = ss ^ (r & 7);                          // inverse-swizzled source slot
      size_t ga = (size_t)(bm * 128 + r) * K + kc + c * 8;
      size_t gb = (size_t)(bn * 128 + r) * K + kc + c * 8;
      int ldst = q * 2048 + w * 512;                 // wave-uniform LDS base (shorts)
      gload16(g.A + ga, &As[ldst]);
      gload16(g.B + gb, &Bs[ldst]);
    }
  };

  stage(0, 0);

  for (int ks = 0; ks < NK; ++ks) {
    if (ks + 1 < NK) {
      stage(ks + 1, (ks + 1) & 1);
      // wait only for stage(ks): exactly the 8 loads of stage(ks+1) remain
      asm volatile("s_waitcnt vmcnt(8)" ::: "memory");
    } else {
      asm volatile("s_waitcnt vmcnt(0)" ::: "memory");
    }
    __builtin_amdgcn_sched_barrier(0);
    __builtin_amdgcn_s_barrier();        // all waves' stage(ks) visible

    const short* As = smem + (ks & 1) * 16384;
    const short* Bs = As + 8192;
#pragma unroll
    for (int kk = 0; kk < 2; ++kk) {
      short8 av[4], bh[4];
#pragma unroll
      for (int mi = 0; mi < 4; ++mi) {
        int row = wm + mi * 16 + l15;
        int eoff = row * 64 + (((kk * 4 + l4) ^ (row & 7)) << 3);
        av[mi] = *(const short8*)&As[eoff];
      }
#pragma unroll
      for (int ni = 0; ni < 4; ++ni) {
        int row = wn + ni * 16 + l15;
        int eoff = row * 64 + (((kk * 4 + l4) ^ (row & 7)) << 3);
        bh[ni] = *(const short8*)&Bs[eoff];
      }
#pragma unroll
      for (int mi = 0; mi < 4; ++mi)
#pragma unroll
        for (int ni = 0; ni < 4; ++ni)
          acc[mi][ni] = __builtin_amdgcn_mfma_f32_16x16x32_f16(
              __builtin_bit_cast(half8, av[mi]), __builtin_bit_cast(half8, bh[ni]),
              acc[mi][ni], 0, 0, 0);
    }
    // my reads of buf[ks&1] retired (rule #18: asm wait + sched fence), then
    // barrier -> all waves done reading; next iteration may overwrite it.
    asm volatile("s_waitcnt lgkmcnt(0)" ::: "memory");
    __builtin_amdgcn_sched_barrier(0);
    __builtin_amdgcn_s_barrier();
  }

  const int gm0 = bm * 128 + wm;
  const int gn0 = bn * 128 + wn;
#pragma unroll
  for (int mi = 0; mi < 4; ++mi) {
#pragma unroll
    for (int ni = 0; ni < 4; ++ni) {
      int n = gn0 + ni * 16 + l15;
#pragma unroll
      for (int r = 0; r < 4; ++r) {
        int m = gm0 + mi * 16 + l4 * 4 + r;
        float v = acc[mi][ni][r];
        if constexpr (EPI == 0) {
          float h = fast_tanh(v + g.bias[n]);
          g.Oh[(size_t)m * UNITS + n] = f2h_bits(h);
        } else if constexpr (EPI == 1) {
          size_t idx = (size_t)m * UNITS + n;
          float h = h2f_bits(g.Hh[idx]);
          g.Oh[idx] = f2h_bits(v * (1.0f - h * h));
        } else {
          if (n < GRAD_COLS)
            g.Og[((size_t)m * NITER + g.iter) * GRAD_COLS + n] = v;
        }
      }
    }
  }
}

template<int EA, int EB>
__global__ __launch_bounds__(256, 2)
void paired_kernel(GArgs A, GArgs B, int nA) {
  __shared__ short smem[32768];        // 2 bufs x (A 8192 + B 8192)
  int id = blockIdx.x;
  if (id < nA) gemm_body<EA>(A, smem, id);
  else         gemm_body<EB>(B, smem, id - nA);
}

template<int E>
__global__ __launch_bounds__(256, 2)
void solo_kernel(GArgs A) {
  __shared__ short smem[32768];
  gemm_body<E>(A, smem, blockIdx.x);
}

// ---------------------------------------------------------------------------
// dot (w[:,i] = H3.W4 + b4) + U3 = (1-H3^2)*W4 + build D for iter i+1
// ---------------------------------------------------------------------------
__global__ __launch_bounds__(256)
void dot_bd_kernel(const unsigned short* __restrict__ H3,
                   const float* __restrict__ W4, const float* __restrict__ b4,
                   const float* __restrict__ x, float* __restrict__ w_out,
                   unsigned short* __restrict__ U,
                   unsigned short* __restrict__ D,
                   int iter, int buildD)
{
  int w = threadIdx.x >> 6, lane = threadIdx.x & 63;
  int b = blockIdx.x * 4 + w;
  size_t base = (size_t)b * UNITS + lane * 8;
  short8 vh = *(const short8*)&H3[base];
  float dot = 0.0f;
  short8 ou;
#pragma unroll
  for (int j = 0; j < 8; ++j) {
    float h = h2f_bits((unsigned short)vh[j]);
    float g = W4[lane * 8 + j];
    dot += h * g;
    ou[j] = (short)f2h_bits((1.0f - h * h) * g);
  }
  *(short8*)&U[base] = ou;
#pragma unroll
  for (int off = 1; off < 64; off <<= 1) dot += __shfl_xor(dot, off);
  float wv = dot + b4[0];
  if (lane == 0) w_out[(size_t)b * NITER + iter] = wv;

  if (buildD) {
    int jn = iter + 1;
#pragma unroll
    for (int cc = 0; cc < 2; ++cc) {
      int c = lane + cc * 64;
      float val;
      if (c < 25 - jn)        val = x[(size_t)b * INSZ + jn + c];
      else if (c < 24)        val = w_out[(size_t)b * NITER + (c - (25 - jn))];
      else if (c == 24)       val = wv;      // w[:, jn-1] just computed, in-register
      else if (c < 100)       val = x[(size_t)b * INSZ + 26 + 3 * jn + (c - 25)];
      else if (c == 100)      val = (float)jn;
      else                    val = 0.0f;
      D[(size_t)b * KPAD + c] = f2h_bits(val);
    }
  }
}

// ---------------------------------------------------------------------------
extern "C" void kernel_launch(void* const* d_in, const int* in_sizes, int n_in,
                              void* d_out, int out_size, void* d_ws, size_t ws_size,
                              hipStream_t stream) {
  const float* x  = (const float*)d_in[0];
  const float* W0 = (const float*)d_in[1];
  const float* b0 = (const float*)d_in[2];
  const float* W1 = (const float*)d_in[3];
  const float* b1 = (const float*)d_in[4];
  const float* W2 = (const float*)d_in[5];
  const float* b2 = (const float*)d_in[6];
  const float* W3 = (const float*)d_in[7];
  const float* b3 = (const float*)d_in[8];
  const float* W4 = (const float*)d_in[9];
  const float* b4 = (const float*)d_in[10];

  float* w_out    = (float*)d_out;                              // (8192, 25)
  float* grad_out = (float*)d_out + (size_t)B_ROWS * NITER;     // (8192, 25, 101)

  char* p = (char*)d_ws;
  auto alloc = [&](size_t elems) { unsigned short* r = (unsigned short*)p; p += elems * 2; return r; };

  unsigned short* TW0 = alloc(512 * KPAD);
  unsigned short* TW1 = alloc(512 * 512);
  unsigned short* TW2 = alloc(512 * 512);
  unsigned short* TW3 = alloc(512 * 512);
  unsigned short* CW0 = alloc(KPAD * 512);
  unsigned short* CW1 = alloc(512 * 512);
  unsigned short* CW2 = alloc(512 * 512);
  unsigned short* CW3 = alloc(512 * 512);

  unsigned short* D = alloc((size_t)B_ROWS * KPAD);

  unsigned short *H[2][4];
  for (int par = 0; par < 2; ++par)
    for (int l = 0; l < 4; ++l)
      H[par][l] = alloc((size_t)B_ROWS * UNITS);
  unsigned short* Ua = alloc((size_t)B_ROWS * UNITS);
  unsigned short* Ub = alloc((size_t)B_ROWS * UNITS);

  prep_kernel<<<1024, 256, 0, stream>>>(W0, W1, W2, W3,
      TW0, TW1, TW2, TW3, CW0, CW1, CW2, CW3);

  build_d_kernel<<<4096, 256, 0, stream>>>(x, D);

  // forward chain for iteration 0 (parity 0)
  {
    GArgs f0 = {D, TW0, KPAD, b0, nullptr, H[0][0], nullptr, 0};
    GArgs f1 = {H[0][0], TW1, 512, b1, nullptr, H[0][1], nullptr, 0};
    GArgs f2 = {H[0][1], TW2, 512, b2, nullptr, H[0][2], nullptr, 0};
    GArgs f3 = {H[0][2], TW3, 512, b3, nullptr, H[0][3], nullptr, 0};
    solo_kernel<0><<<256, 256, 0, stream>>>(f0);
    solo_kernel<0><<<256, 256, 0, stream>>>(f1);
    solo_kernel<0><<<256, 256, 0, stream>>>(f2);
    solo_kernel<0><<<256, 256, 0, stream>>>(f3);
  }

  for (int i = 0; i < NITER; ++i) {
    int pp = i & 1, q = pp ^ 1;
    bool more = (i < NITER - 1);

    dot_bd_kernel<<<2048, 256, 0, stream>>>(H[pp][3], W4, b4, x, w_out,
                                            Ua, D, i, more ? 1 : 0);

    GArgs bw3 = {Ua, CW3, 512, nullptr, H[pp][2], Ub, nullptr, 0};
    GArgs bw2 = {Ub, CW2, 512, nullptr, H[pp][1], Ua, nullptr, 0};
    GArgs bw1 = {Ua, CW1, 512, nullptr, H[pp][0], Ub, nullptr, 0};
    GArgs gr0 = {Ub, CW0, 512, nullptr, nullptr, nullptr, grad_out, i};

    if (more) {
      GArgs f0 = {D, TW0, KPAD, b0, nullptr, H[q][0], nullptr, 0};
      GArgs f1 = {H[q][0], TW1, 512, b1, nullptr, H[q][1], nullptr, 0};
      GArgs f2 = {H[q][1], TW2, 512, b2, nullptr, H[q][2], nullptr, 0};
      GArgs f3 = {H[q][2], TW3, 512, b3, nullptr, H[q][3], nullptr, 0};
      paired_kernel<1, 0><<<512, 256, 0, stream>>>(bw3, f0, 256);
      paired_kernel<1, 0><<<512, 256, 0, stream>>>(bw2, f1, 256);
      paired_kernel<1, 0><<<512, 256, 0, stream>>>(bw1, f2, 256);
      paired_kernel<2, 0><<<320, 256, 0, stream>>>(gr0, f3, 64);
    } else {
      solo_kernel<1><<<256, 256, 0, stream>>>(bw3);
      solo_kernel<1><<<256, 256, 0, stream>>>(bw2);
      solo_kernel<1><<<256, 256, 0, stream>>>(bw1);
      solo_kernel<2><<<64, 256, 0, stream>>>(gr0);
    }
  }

  (void)in_sizes; (void)n_in; (void)out_size; (void)ws_size;
}